// Round 2
// baseline (560.749 us; speedup 1.0000x reference)
//
#include <hip/hip_runtime.h>
#include <stdint.h>
#include <stddef.h>

#define B_ 8
#define N_ 2048
#define C_ 2048
#define D_ 256
#define H_ 256

typedef __bf16 bf16x8 __attribute__((ext_vector_type(8)));
typedef __bf16 bf16x4 __attribute__((ext_vector_type(4)));
typedef float f32x4 __attribute__((ext_vector_type(4)));

#define MFMA16(a, b, c) __builtin_amdgcn_mfma_f32_16x16x32_bf16((a), (b), (c), 0, 0, 0)

// ---------------------------------------------------------------------------
// K0: collapse score projections to vectors (rank-1 score factorization).
// ---------------------------------------------------------------------------
__global__ __launch_bounds__(256) void k0_vectors(
    const float* __restrict__ oma_q_w, const float* __restrict__ oma_q_b,
    const float* __restrict__ oma_kv_w, const float* __restrict__ oma_kv_b,
    const float* __restrict__ oma_s_w, const float* __restrict__ oma_s_b,
    const float* __restrict__ sa_w_w, const float* __restrict__ sa_w_b,
    const float* __restrict__ sa_s_w, const float* __restrict__ sa_s_b,
    float* __restrict__ wq_v, float* __restrict__ wk_v,
    float* __restrict__ wq2_v, float* __restrict__ wk2_v,
    float* __restrict__ sb)
{
    int d = threadIdx.x;
    float a0 = 0.f, a1 = 0.f, a2 = 0.f, a3 = 0.f;
    for (int h = 0; h < 256; ++h) {
        a0 += oma_q_w[h * 256 + d] * oma_s_w[h];
        a1 += oma_kv_w[h * 256 + d] * oma_s_w[256 + h];
        a2 += sa_w_w[h * 256 + d] * sa_s_w[h];
        a3 += sa_w_w[(256 + h) * 256 + d] * sa_s_w[256 + h];
    }
    wq_v[d] = a0; wk_v[d] = a1; wq2_v[d] = a2; wk2_v[d] = a3;

    int h = d;
    float p1 = oma_q_b[h] * oma_s_w[h] + oma_kv_b[h] * oma_s_w[256 + h];
    float p2 = sa_w_b[h] * sa_s_w[h] + sa_w_b[256 + h] * sa_s_w[256 + h];
    for (int o = 32; o; o >>= 1) { p1 += __shfl_xor(p1, o); p2 += __shfl_xor(p2, o); }
    __shared__ float redA[4], redB[4];
    int wv = threadIdx.x >> 6;
    if ((threadIdx.x & 63) == 0) { redA[wv] = p1; redB[wv] = p2; }
    __syncthreads();
    if (threadIdx.x == 0) {
        sb[0] = redA[0] + redA[1] + redA[2] + redA[3] + oma_s_b[0];
        sb[1] = redB[0] + redB[1] + redB[2] + redB[3] + sa_s_b[0];
    }
}

// ---------------------------------------------------------------------------
// K1: fold output projections through mix -> Wcat (bf16) + b_total.
// ---------------------------------------------------------------------------
__global__ __launch_bounds__(256) void k1_wcat(
    const float* __restrict__ mix_w, const float* __restrict__ mix_b,
    const float* __restrict__ oma_o_w, const float* __restrict__ oma_o_b,
    const float* __restrict__ sa_o_w, const float* __restrict__ sa_o_b,
    __bf16* __restrict__ Wcat, float* __restrict__ b_total)
{
    int d = blockIdx.x, h = threadIdx.x;
    const float* mwr = mix_w + d * 512;
    float w1 = 0.f, w2 = 0.f;
    for (int e = 0; e < 256; ++e) {
        w1 += mwr[e] * oma_o_w[e * 256 + h];
        w2 += mwr[256 + e] * sa_o_w[e * 256 + h];
    }
    Wcat[d * 512 + h] = (__bf16)w1;
    Wcat[d * 512 + 256 + h] = (__bf16)w2;

    float pb = mwr[h] * oma_o_b[h] + mwr[256 + h] * sa_o_b[h];
    for (int o = 32; o; o >>= 1) pb += __shfl_xor(pb, o);
    __shared__ float red[4];
    if ((h & 63) == 0) red[h >> 6] = pb;
    __syncthreads();
    if (h == 0) b_total[d] = mix_b[d] + red[0] + red[1] + red[2] + red[3];
}

// ---------------------------------------------------------------------------
// K2: per-row score scalars (one wave per row).
// ---------------------------------------------------------------------------
__global__ __launch_bounds__(256) void k2_scores(
    const float* __restrict__ op, const float* __restrict__ mach,
    const float* __restrict__ wq_v, const float* __restrict__ wk_v,
    const float* __restrict__ wq2_v, const float* __restrict__ wk2_v,
    const float* __restrict__ sb,
    float* __restrict__ sqp, float* __restrict__ skv,
    float* __restrict__ sq2p, float* __restrict__ sk2v)
{
    int t = threadIdx.x, lane = t & 63, wv = t >> 6;
    size_t n = (size_t)blockIdx.x * 4 + wv;
    const float4 mf = *(const float4*)(mach + n * 256 + lane * 4);
    const float4 of = *(const float4*)(op + n * 256 + lane * 4);
    const float4 q4 = *(const float4*)(wq_v + lane * 4);
    const float4 k4 = *(const float4*)(wk_v + lane * 4);
    const float4 q24 = *(const float4*)(wq2_v + lane * 4);
    const float4 k24 = *(const float4*)(wk2_v + lane * 4);
    float s1 = mf.x * q4.x + mf.y * q4.y + mf.z * q4.z + mf.w * q4.w;
    float s2 = of.x * k4.x + of.y * k4.y + of.z * k4.z + of.w * k4.w;
    float s3 = mf.x * q24.x + mf.y * q24.y + mf.z * q24.z + mf.w * q24.w;
    float s4 = mf.x * k24.x + mf.y * k24.y + mf.z * k24.z + mf.w * k24.w;
    for (int o = 32; o; o >>= 1) {
        s1 += __shfl_xor(s1, o); s2 += __shfl_xor(s2, o);
        s3 += __shfl_xor(s3, o); s4 += __shfl_xor(s4, o);
    }
    if (lane == 0) {
        sqp[n] = s1 + sb[0]; skv[n] = s2;
        sq2p[n] = s3 + sb[1]; sk2v[n] = s4;
    }
}

// ---------------------------------------------------------------------------
// K3: value projections -> vt[which][b][h][c] (bf16, h-major so attention
// B-fragments are contiguous along c).
// One block per (which, b, c-tile of 64): stages the X tile (64 c-rows x 256 d)
// ONCE, loops over the 4 weight h-tiles. X HBM traffic: 34 MB (was 134 MB).
// ---------------------------------------------------------------------------
__global__ __launch_bounds__(256, 2) void k3_vgemm(
    const float* __restrict__ op, const float* __restrict__ mach,
    const float* __restrict__ oma_kv_w, const float* __restrict__ sa_w_w,
    __bf16* __restrict__ vt)
{
    __shared__ __attribute__((aligned(16))) __bf16 Xs[64][264];
    __shared__ __attribute__((aligned(16))) __bf16 As[64][264];
    int t = threadIdx.x;
    int bid = blockIdx.x;
    int which = bid >> 8;
    int r = bid & 255;
    int b = r >> 5;
    int ct = r & 31;

    const float* Wbase = which ? (sa_w_w + 512 * 256) : (oma_kv_w + 256 * 256);
    const float* Xglob = (which ? mach : op) + ((size_t)b * N_ + ct * 64) * 256;

    int lane = t & 63, wv = t >> 6;
    int l15 = lane & 15, qo = (lane >> 4) * 8;

    // stage X tile once (fp32 -> bf16)
    #pragma unroll
    for (int p = 0; p < 16; ++p) {
        int row = p * 4 + wv;
        float4 xv = *(const float4*)(Xglob + (size_t)row * 256 + lane * 4);
        bf16x4 x4;
        x4[0] = (__bf16)xv.x; x4[1] = (__bf16)xv.y; x4[2] = (__bf16)xv.z; x4[3] = (__bf16)xv.w;
        *(bf16x4*)&Xs[row][lane * 4] = x4;
    }

    for (int ht = 0; ht < 4; ++ht) {
        __syncthreads();   // prior store phase read As
        const float* Ag = Wbase + (size_t)ht * 64 * 256;
        #pragma unroll
        for (int p = 0; p < 16; ++p) {
            int row = p * 4 + wv;
            float4 av = *(const float4*)(Ag + (size_t)row * 256 + lane * 4);
            bf16x4 a4;
            a4[0] = (__bf16)av.x; a4[1] = (__bf16)av.y; a4[2] = (__bf16)av.z; a4[3] = (__bf16)av.w;
            *(bf16x4*)&As[row][lane * 4] = a4;
        }
        __syncthreads();

        f32x4 acc[4] = {};
        #pragma unroll
        for (int kb = 0; kb < 8; ++kb) {
            bf16x8 bfr = *(const bf16x8*)&Xs[16 * wv + l15][kb * 32 + qo];
            #pragma unroll
            for (int rt = 0; rt < 4; ++rt) {
                bf16x8 afr = *(const bf16x8*)&As[16 * rt + l15][kb * 32 + qo];
                acc[rt] = MFMA16(afr, bfr, acc[rt]);
            }
        }
        __syncthreads();

        // pack C[h][c] into As for coalesced stores
        #pragma unroll
        for (int rt = 0; rt < 4; ++rt)
            #pragma unroll
            for (int j = 0; j < 4; ++j)
                As[16 * rt + (lane >> 4) * 4 + j][16 * wv + l15] = (__bf16)acc[rt][j];
        __syncthreads();

        int hh = t >> 2, cb = (t & 3) * 16;
        __bf16* orow = vt + (((size_t)(which * 8 + b)) * 256 + ht * 64 + hh) * 2048 + ct * 64 + cb;
        *(bf16x8*)(orow) = *(const bf16x8*)&As[hh][cb];
        *(bf16x8*)(orow + 8) = *(const bf16x8*)&As[hh][cb + 8];
    }
}

// ---------------------------------------------------------------------------
// K4: fused masked-softmax attention. 32-row m-tiles -> grid 1024 = exactly
// 4 blocks/CU (LDS = 40960 B/block, 4x = 160 KiB exactly). 2-deep mask
// prefetch in registers; eA is XOR-swizzled (16B chunk ^ row&7) instead of
// padded to fit the LDS budget. rowsum aliased into vB's tail.
// ---------------------------------------------------------------------------
__global__ __launch_bounds__(256, 4) void k4_attn(
    const float* __restrict__ tmask, const float* __restrict__ smask,
    const float* __restrict__ sqp, const float* __restrict__ skv,
    const float* __restrict__ sq2p, const float* __restrict__ sk2v,
    const __bf16* __restrict__ vt,
    __bf16* __restrict__ wfcat)
{
    __shared__ __attribute__((aligned(16))) __bf16 eA[32][64];   //  4096 B
    __shared__ __attribute__((aligned(16))) __bf16 vB[256][72];  // 36864 B

    int t = threadIdx.x;
    int bid = blockIdx.x;
    int which = bid >> 9;
    int r = bid & 511;
    int b = r >> 6;
    int m0 = (r & 63) * 32;

    const float* mask = (which ? smask : tmask) + ((size_t)b * N_ + m0) * C_;
    const float* sqrow = (which ? sq2p : sqp) + b * N_ + m0;
    const float* skrow = (which ? sk2v : skv) + b * N_;
    const __bf16* vbase = vt + ((size_t)(which * 8 + b)) * 256 * 2048;

    int lane = t & 63, wv = t >> 6;
    int l15 = lane & 15, qo = (lane >> 4) * 8;
    int mrow = t >> 3;          // 0..31 : my e-row
    int cc = t & 7;             // my 16B chunk within the 64-col slab
    int vh = t >> 3;            // 0..31 : v staging row base
    int vc = (t & 7) * 8;

    float sqv = sqrow[mrow];
    float psum = 0.f;
    f32x4 acc[2][4] = {};

    bf16x8 vv[8];
    float mk[2][8], skc[2][8];

    auto load_mask = [&](int c0, int s) {
        #pragma unroll
        for (int i = 0; i < 2; ++i) {
            float4 m4 = *(const float4*)(mask + (size_t)mrow * C_ + c0 + cc * 8 + i * 4);
            float4 s4 = *(const float4*)(skrow + c0 + cc * 8 + i * 4);
            mk[s][4 * i + 0] = m4.x; mk[s][4 * i + 1] = m4.y;
            mk[s][4 * i + 2] = m4.z; mk[s][4 * i + 3] = m4.w;
            skc[s][4 * i + 0] = s4.x; skc[s][4 * i + 1] = s4.y;
            skc[s][4 * i + 2] = s4.z; skc[s][4 * i + 3] = s4.w;
        }
    };
    auto load_v = [&](int c0) {
        #pragma unroll
        for (int p = 0; p < 8; ++p)
            vv[p] = *(const bf16x8*)(vbase + (size_t)(p * 32 + vh) * 2048 + c0 + vc);
    };

    load_mask(0, 0);
    load_v(0);
    load_mask(64, 1);

    for (int c0 = 0; c0 < C_; c0 += 64) {
        int s = (c0 >> 6) & 1;
        // stage v tile from prefetched regs
        #pragma unroll
        for (int p = 0; p < 8; ++p)
            *(bf16x8*)&vB[p * 32 + vh][vc] = vv[p];
        // e tile (fp32 math, bf16 store, swizzled chunk)
        bf16x8 e0;
        #pragma unroll
        for (int i = 0; i < 8; ++i) {
            float sc = sqv + skc[s][i];
            sc = sc > 0.f ? sc : 0.01f * sc;
            float e = __expf(sc * mk[s][i]);
            psum += e;
            e0[i] = (__bf16)e;
        }
        *(bf16x8*)&eA[mrow][(cc ^ (mrow & 7)) * 8] = e0;
        __syncthreads();
        // prefetch: v 1 chunk ahead (L2-resident), mask/sk 2 chunks ahead (HBM)
        load_v((c0 + 64) & 2047);
        load_mask((c0 + 128) & 2047, s);
        #pragma unroll
        for (int kb = 0; kb < 2; ++kb) {
            bf16x8 afr[2];
            #pragma unroll
            for (int rt = 0; rt < 2; ++rt)
                afr[rt] = *(const bf16x8*)&eA[16 * rt + l15][((kb * 4 + (lane >> 4)) ^ (l15 & 7)) * 8];
            #pragma unroll
            for (int ctile = 0; ctile < 4; ++ctile) {
                bf16x8 bfr = *(const bf16x8*)&vB[64 * wv + 16 * ctile + l15][kb * 32 + qo];
                #pragma unroll
                for (int rt = 0; rt < 2; ++rt)
                    acc[rt][ctile] = MFMA16(afr[rt], bfr, acc[rt][ctile]);
            }
        }
        __syncthreads();
    }

    // rowsum: 8 threads per row hold disjoint column partials
    float* rowsum = (float*)(&vB[0][0] + 9000);   // past the obuf region
    float rs = psum;
    rs += __shfl_xor(rs, 1);
    rs += __shfl_xor(rs, 2);
    rs += __shfl_xor(rs, 4);
    if ((t & 7) == 0) rowsum[mrow] = rs;
    __syncthreads();

    // normalize, pack [32][256] (stride 264) into vB head, coalesced store
    __bf16* obuf = &vB[0][0];
    #pragma unroll
    for (int rt = 0; rt < 2; ++rt) {
        #pragma unroll
        for (int j = 0; j < 4; ++j) {
            int m = 16 * rt + (lane >> 4) * 4 + j;
            float inv = __builtin_amdgcn_rcpf(rowsum[m]);
            #pragma unroll
            for (int ctile = 0; ctile < 4; ++ctile)
                obuf[m * 264 + 64 * wv + 16 * ctile + l15] = (__bf16)(acc[rt][ctile][j] * inv);
        }
    }
    __syncthreads();
    int m = t >> 3, cb = (t & 7) * 32;
    __bf16* wrow = wfcat + ((size_t)(b * N_ + m0 + m)) * 512 + which * 256 + cb;
    #pragma unroll
    for (int k = 0; k < 4; ++k)
        *(bf16x8*)(wrow + k * 8) = *(const bf16x8*)&obuf[m * 264 + cb + k * 8];
}

// ---------------------------------------------------------------------------
// K5: out[n][d] = wfcat[n][:512] . Wcat[d][:512] + b_total[d]   (fp32 out)
// ---------------------------------------------------------------------------
__global__ __launch_bounds__(256, 2) void k5_out(
    const __bf16* __restrict__ wfcat, const __bf16* __restrict__ Wcat,
    const float* __restrict__ b_total, float* __restrict__ out)
{
    __shared__ __attribute__((aligned(16))) __bf16 As[64][72];
    __shared__ __attribute__((aligned(16))) __bf16 Bs[256][72];
    __shared__ float bias[256];
    int t = threadIdx.x;
    int n0 = blockIdx.x * 64;
    int lane = t & 63, wv = t >> 6, l15 = lane & 15, qo = (lane >> 4) * 8;
    bias[t] = b_total[t];
    int ar = t >> 3;          // 0..31
    int ac = (t & 7) * 8;
    f32x4 acc[4][4] = {};

    for (int k0 = 0; k0 < 512; k0 += 64) {
        #pragma unroll
        for (int p = 0; p < 2; ++p)
            *(bf16x8*)&As[p * 32 + ar][ac] =
                *(const bf16x8*)(wfcat + (size_t)(n0 + p * 32 + ar) * 512 + k0 + ac);
        #pragma unroll
        for (int p = 0; p < 8; ++p)
            *(bf16x8*)&Bs[p * 32 + ar][ac] =
                *(const bf16x8*)(Wcat + (size_t)(p * 32 + ar) * 512 + k0 + ac);
        __syncthreads();
        #pragma unroll
        for (int kb = 0; kb < 2; ++kb) {
            bf16x8 afr[4];
            #pragma unroll
            for (int rt = 0; rt < 4; ++rt)
                afr[rt] = *(const bf16x8*)&As[16 * rt + l15][kb * 32 + qo];
            #pragma unroll
            for (int ct = 0; ct < 4; ++ct) {
                bf16x8 bfr = *(const bf16x8*)&Bs[64 * wv + 16 * ct + l15][kb * 32 + qo];
                #pragma unroll
                for (int rt = 0; rt < 4; ++rt)
                    acc[rt][ct] = MFMA16(afr[rt], bfr, acc[rt][ct]);
            }
        }
        __syncthreads();
    }
    #pragma unroll
    for (int rt = 0; rt < 4; ++rt) {
        #pragma unroll
        for (int ct = 0; ct < 4; ++ct) {
            int d = 64 * wv + 16 * ct + l15;
            float bv = bias[d];
            #pragma unroll
            for (int j = 0; j < 4; ++j) {
                int m = 16 * rt + (lane >> 4) * 4 + j;
                out[(size_t)(n0 + m) * 256 + d] = acc[rt][ct][j] + bv;
            }
        }
    }
}

// ---------------------------------------------------------------------------
extern "C" void kernel_launch(void* const* d_in, const int* in_sizes, int n_in,
                              void* d_out, int out_size, void* d_ws, size_t ws_size,
                              hipStream_t stream)
{
    const float* op_feat  = (const float*)d_in[0];
    const float* mach_feat= (const float*)d_in[1];
    const float* tmask    = (const float*)d_in[2];
    const float* smask    = (const float*)d_in[3];
    const float* oma_q_w  = (const float*)d_in[4];
    const float* oma_q_b  = (const float*)d_in[5];
    const float* oma_kv_w = (const float*)d_in[6];
    const float* oma_kv_b = (const float*)d_in[7];
    const float* oma_s_w  = (const float*)d_in[8];
    const float* oma_s_b  = (const float*)d_in[9];
    const float* oma_o_w  = (const float*)d_in[10];
    const float* oma_o_b  = (const float*)d_in[11];
    const float* sa_w_w   = (const float*)d_in[12];
    const float* sa_w_b   = (const float*)d_in[13];
    const float* sa_s_w   = (const float*)d_in[14];
    const float* sa_s_b   = (const float*)d_in[15];
    const float* sa_o_w   = (const float*)d_in[16];
    const float* sa_o_b   = (const float*)d_in[17];
    const float* mix_w    = (const float*)d_in[18];
    const float* mix_b    = (const float*)d_in[19];

    char* ws = (char*)d_ws;
    float* wq_v   = (float*)(ws + 0);
    float* wk_v   = (float*)(ws + 1024);
    float* wq2_v  = (float*)(ws + 2048);
    float* wk2_v  = (float*)(ws + 3072);
    float* sb     = (float*)(ws + 4096);
    float* btot   = (float*)(ws + 4352);
    float* sqp    = (float*)(ws + 8192);
    float* skv    = (float*)(ws + 73728);
    float* sq2p   = (float*)(ws + 139264);
    float* sk2v   = (float*)(ws + 204800);
    __bf16* Wcat  = (__bf16*)(ws + 270336);    //  256 KB
    __bf16* vt    = (__bf16*)(ws + 532480);    //   16 MB : [2][8][256][2048]
    __bf16* wfcat = (__bf16*)(ws + 17309696);  //   16 MB : [16384][512]
    float* outp   = (float*)d_out;

    k0_vectors<<<1, 256, 0, stream>>>(oma_q_w, oma_q_b, oma_kv_w, oma_kv_b,
                                      oma_s_w, oma_s_b, sa_w_w, sa_w_b,
                                      sa_s_w, sa_s_b, wq_v, wk_v, wq2_v, wk2_v, sb);
    k1_wcat<<<256, 256, 0, stream>>>(mix_w, mix_b, oma_o_w, oma_o_b,
                                     sa_o_w, sa_o_b, Wcat, btot);
    k2_scores<<<4096, 256, 0, stream>>>(op_feat, mach_feat, wq_v, wk_v, wq2_v, wk2_v,
                                        sb, sqp, skv, sq2p, sk2v);
    k3_vgemm<<<512, 256, 0, stream>>>(op_feat, mach_feat, oma_kv_w, sa_w_w, vt);
    k4_attn<<<1024, 256, 0, stream>>>(tmask, smask, sqp, skv, sq2p, sk2v, vt, wfcat);
    k5_out<<<256, 256, 0, stream>>>(wfcat, Wcat, btot, outp);
}

// Round 3
// 523.767 us; speedup vs baseline: 1.0706x; 1.0706x over previous
//
#include <hip/hip_runtime.h>
#include <stdint.h>
#include <stddef.h>

#define B_ 8
#define N_ 2048
#define C_ 2048
#define D_ 256
#define H_ 256

typedef __bf16 bf16x8 __attribute__((ext_vector_type(8)));
typedef __bf16 bf16x4 __attribute__((ext_vector_type(4)));
typedef float f32x4 __attribute__((ext_vector_type(4)));

#define MFMA16(a, b, c) __builtin_amdgcn_mfma_f32_16x16x32_bf16((a), (b), (c), 0, 0, 0)

// ---------------------------------------------------------------------------
// K0: collapse score projections to vectors (rank-1 score factorization).
// 4 blocks, one output vector each; block 0 also does the scalar biases.
// ---------------------------------------------------------------------------
__global__ __launch_bounds__(256) void k0_vectors(
    const float* __restrict__ oma_q_w, const float* __restrict__ oma_q_b,
    const float* __restrict__ oma_kv_w, const float* __restrict__ oma_kv_b,
    const float* __restrict__ oma_s_w, const float* __restrict__ oma_s_b,
    const float* __restrict__ sa_w_w, const float* __restrict__ sa_w_b,
    const float* __restrict__ sa_s_w, const float* __restrict__ sa_s_b,
    float* __restrict__ wq_v, float* __restrict__ wk_v,
    float* __restrict__ wq2_v, float* __restrict__ wk2_v,
    float* __restrict__ sb)
{
    int d = threadIdx.x;
    int w = blockIdx.x;
    const float* M;
    const float* svec;
    float* outv;
    if (w == 0)      { M = oma_q_w;            svec = oma_s_w;       outv = wq_v;  }
    else if (w == 1) { M = oma_kv_w;           svec = oma_s_w + 256; outv = wk_v;  }
    else if (w == 2) { M = sa_w_w;             svec = sa_s_w;        outv = wq2_v; }
    else             { M = sa_w_w + 256 * 256; svec = sa_s_w + 256;  outv = wk2_v; }
    float a = 0.f;
    #pragma unroll 8
    for (int h = 0; h < 256; ++h)
        a += M[h * 256 + d] * svec[h];
    outv[d] = a;

    if (w == 0) {
        int h = d;
        float p1 = oma_q_b[h] * oma_s_w[h] + oma_kv_b[h] * oma_s_w[256 + h];
        float p2 = sa_w_b[h] * sa_s_w[h] + sa_w_b[256 + h] * sa_s_w[256 + h];
        for (int o = 32; o; o >>= 1) { p1 += __shfl_xor(p1, o); p2 += __shfl_xor(p2, o); }
        __shared__ float redA[4], redB[4];
        int wvv = threadIdx.x >> 6;
        if ((threadIdx.x & 63) == 0) { redA[wvv] = p1; redB[wvv] = p2; }
        __syncthreads();
        if (threadIdx.x == 0) {
            sb[0] = redA[0] + redA[1] + redA[2] + redA[3] + oma_s_b[0];
            sb[1] = redB[0] + redB[1] + redB[2] + redB[3] + sa_s_b[0];
        }
    }
}

// ---------------------------------------------------------------------------
// K1: fold output projections through mix -> Wcat (bf16) + b_total.
// ---------------------------------------------------------------------------
__global__ __launch_bounds__(256) void k1_wcat(
    const float* __restrict__ mix_w, const float* __restrict__ mix_b,
    const float* __restrict__ oma_o_w, const float* __restrict__ oma_o_b,
    const float* __restrict__ sa_o_w, const float* __restrict__ sa_o_b,
    __bf16* __restrict__ Wcat, float* __restrict__ b_total)
{
    int d = blockIdx.x, h = threadIdx.x;
    const float* mwr = mix_w + d * 512;
    float w1 = 0.f, w2 = 0.f;
    for (int e = 0; e < 256; ++e) {
        w1 += mwr[e] * oma_o_w[e * 256 + h];
        w2 += mwr[256 + e] * sa_o_w[e * 256 + h];
    }
    Wcat[d * 512 + h] = (__bf16)w1;
    Wcat[d * 512 + 256 + h] = (__bf16)w2;

    float pb = mwr[h] * oma_o_b[h] + mwr[256 + h] * sa_o_b[h];
    for (int o = 32; o; o >>= 1) pb += __shfl_xor(pb, o);
    __shared__ float red[4];
    if ((h & 63) == 0) red[h >> 6] = pb;
    __syncthreads();
    if (h == 0) b_total[d] = mix_b[d] + red[0] + red[1] + red[2] + red[3];
}

// ---------------------------------------------------------------------------
// K2: per-row score scalars (one wave per row).
// ---------------------------------------------------------------------------
__global__ __launch_bounds__(256) void k2_scores(
    const float* __restrict__ op, const float* __restrict__ mach,
    const float* __restrict__ wq_v, const float* __restrict__ wk_v,
    const float* __restrict__ wq2_v, const float* __restrict__ wk2_v,
    const float* __restrict__ sb,
    float* __restrict__ sqp, float* __restrict__ skv,
    float* __restrict__ sq2p, float* __restrict__ sk2v)
{
    int t = threadIdx.x, lane = t & 63, wv = t >> 6;
    size_t n = (size_t)blockIdx.x * 4 + wv;
    const float4 mf = *(const float4*)(mach + n * 256 + lane * 4);
    const float4 of = *(const float4*)(op + n * 256 + lane * 4);
    const float4 q4 = *(const float4*)(wq_v + lane * 4);
    const float4 k4 = *(const float4*)(wk_v + lane * 4);
    const float4 q24 = *(const float4*)(wq2_v + lane * 4);
    const float4 k24 = *(const float4*)(wk2_v + lane * 4);
    float s1 = mf.x * q4.x + mf.y * q4.y + mf.z * q4.z + mf.w * q4.w;
    float s2 = of.x * k4.x + of.y * k4.y + of.z * k4.z + of.w * k4.w;
    float s3 = mf.x * q24.x + mf.y * q24.y + mf.z * q24.z + mf.w * q24.w;
    float s4 = mf.x * k24.x + mf.y * k24.y + mf.z * k24.z + mf.w * k24.w;
    for (int o = 32; o; o >>= 1) {
        s1 += __shfl_xor(s1, o); s2 += __shfl_xor(s2, o);
        s3 += __shfl_xor(s3, o); s4 += __shfl_xor(s4, o);
    }
    if (lane == 0) {
        sqp[n] = s1 + sb[0]; skv[n] = s2;
        sq2p[n] = s3 + sb[1]; sk2v[n] = s4;
    }
}

// ---------------------------------------------------------------------------
// K3: value projections -> vt[which][b][h][c] (bf16). One block per
// (which,b,c-tile 64); stages X tile once, loops the 4 weight h-tiles.
// ---------------------------------------------------------------------------
__global__ __launch_bounds__(256, 2) void k3_vgemm(
    const float* __restrict__ op, const float* __restrict__ mach,
    const float* __restrict__ oma_kv_w, const float* __restrict__ sa_w_w,
    __bf16* __restrict__ vt)
{
    __shared__ __attribute__((aligned(16))) __bf16 Xs[64][264];
    __shared__ __attribute__((aligned(16))) __bf16 As[64][264];
    int t = threadIdx.x;
    int bid = blockIdx.x;
    int which = bid >> 8;
    int r = bid & 255;
    int b = r >> 5;
    int ct = r & 31;

    const float* Wbase = which ? (sa_w_w + 512 * 256) : (oma_kv_w + 256 * 256);
    const float* Xglob = (which ? mach : op) + ((size_t)b * N_ + ct * 64) * 256;

    int lane = t & 63, wv = t >> 6;
    int l15 = lane & 15, qo = (lane >> 4) * 8;

    #pragma unroll
    for (int p = 0; p < 16; ++p) {
        int row = p * 4 + wv;
        float4 xv = *(const float4*)(Xglob + (size_t)row * 256 + lane * 4);
        bf16x4 x4;
        x4[0] = (__bf16)xv.x; x4[1] = (__bf16)xv.y; x4[2] = (__bf16)xv.z; x4[3] = (__bf16)xv.w;
        *(bf16x4*)&Xs[row][lane * 4] = x4;
    }

    for (int ht = 0; ht < 4; ++ht) {
        __syncthreads();
        const float* Ag = Wbase + (size_t)ht * 64 * 256;
        #pragma unroll
        for (int p = 0; p < 16; ++p) {
            int row = p * 4 + wv;
            float4 av = *(const float4*)(Ag + (size_t)row * 256 + lane * 4);
            bf16x4 a4;
            a4[0] = (__bf16)av.x; a4[1] = (__bf16)av.y; a4[2] = (__bf16)av.z; a4[3] = (__bf16)av.w;
            *(bf16x4*)&As[row][lane * 4] = a4;
        }
        __syncthreads();

        f32x4 acc[4] = {};
        #pragma unroll
        for (int kb = 0; kb < 8; ++kb) {
            bf16x8 bfr = *(const bf16x8*)&Xs[16 * wv + l15][kb * 32 + qo];
            #pragma unroll
            for (int rt = 0; rt < 4; ++rt) {
                bf16x8 afr = *(const bf16x8*)&As[16 * rt + l15][kb * 32 + qo];
                acc[rt] = MFMA16(afr, bfr, acc[rt]);
            }
        }
        __syncthreads();

        #pragma unroll
        for (int rt = 0; rt < 4; ++rt)
            #pragma unroll
            for (int j = 0; j < 4; ++j)
                As[16 * rt + (lane >> 4) * 4 + j][16 * wv + l15] = (__bf16)acc[rt][j];
        __syncthreads();

        int hh = t >> 2, cb = (t & 3) * 16;
        __bf16* orow = vt + (((size_t)(which * 8 + b)) * 256 + ht * 64 + hh) * 2048 + ct * 64 + cb;
        *(bf16x8*)(orow) = *(const bf16x8*)&As[hh][cb];
        *(bf16x8*)(orow + 8) = *(const bf16x8*)&As[hh][cb + 8];
    }
}

// ---------------------------------------------------------------------------
// K4: fused masked-softmax attention, c-SPLIT in 2. m-tile 64 (as R0, which
// was the faster shape), grid 1024 = 4 blocks/CU. LDS exactly 40960 B
// (XOR-swizzled pad-free eA/vB). Writes UNNORMALIZED bf16 partials:
// c-half 0 -> P0 (ws), c-half 1 -> P1 (d_out used as scratch), plus per-row
// partial sums rsP. Mask bytes read exactly once; v-slice demand unchanged
// vs R0 (each block reads half a slice).
// ---------------------------------------------------------------------------
__global__ __launch_bounds__(256, 4) void k4_attn(
    const float* __restrict__ tmask, const float* __restrict__ smask,
    const float* __restrict__ sqp, const float* __restrict__ skv,
    const float* __restrict__ sq2p, const float* __restrict__ sk2v,
    const __bf16* __restrict__ vt,
    __bf16* __restrict__ P0, __bf16* __restrict__ P1,
    float* __restrict__ rsP)
{
    __shared__ __attribute__((aligned(16))) __bf16 eA[64 * 64];   //  8 KB
    __shared__ __attribute__((aligned(16))) __bf16 vB[256 * 64];  // 32 KB

    int t = threadIdx.x;
    int bid = blockIdx.x;
    int which = bid >> 9;
    int r = bid & 511;
    int b = r >> 6;
    int mtile = (r & 63) >> 1;
    int ch = r & 1;
    int m0 = mtile * 64;
    int cbase = ch * 1024;

    const float* mask = (which ? smask : tmask) + ((size_t)b * N_ + m0) * C_ + cbase;
    const float* sqrow = (which ? sq2p : sqp) + b * N_ + m0;
    const float* skrow = (which ? sk2v : skv) + b * N_ + cbase;
    const __bf16* vbase = vt + ((size_t)(which * 8 + b)) * 256 * 2048 + cbase;

    int lane = t & 63, wv = t >> 6;
    int l15 = lane & 15, quad = lane >> 4;
    int mrow = t >> 2, cq = t & 3;       // e tile: row 0..63, 16-col slice
    int vh = t >> 3, vcc = t & 7;        // v staging: row-in-32-group, chunk

    float sqv = sqrow[mrow];
    float psum = 0.f;
    f32x4 acc[4][4] = {};
    bf16x8 vv[8];
    float mk[16], skc[16];

    auto load_mask = [&](int c0) {
        #pragma unroll
        for (int i = 0; i < 4; ++i) {
            float4 m4 = *(const float4*)(mask + (size_t)mrow * C_ + c0 + cq * 16 + i * 4);
            mk[4 * i + 0] = m4.x; mk[4 * i + 1] = m4.y;
            mk[4 * i + 2] = m4.z; mk[4 * i + 3] = m4.w;
        }
        #pragma unroll
        for (int i = 0; i < 4; ++i) {
            float4 s4 = *(const float4*)(skrow + c0 + cq * 16 + i * 4);
            skc[4 * i + 0] = s4.x; skc[4 * i + 1] = s4.y;
            skc[4 * i + 2] = s4.z; skc[4 * i + 3] = s4.w;
        }
    };
    auto load_v = [&](int c0) {
        #pragma unroll
        for (int p = 0; p < 8; ++p)
            vv[p] = *(const bf16x8*)(vbase + (size_t)(p * 32 + vh) * 2048 + c0 + vcc * 8);
    };
    load_mask(0);
    load_v(0);

    for (int c0 = 0; c0 < 1024; c0 += 64) {
        // stage v (phys chunk = vcc ^ (row&7))
        #pragma unroll
        for (int p = 0; p < 8; ++p) {
            int row = p * 32 + vh;
            *(bf16x8*)&vB[row * 64 + (vcc ^ (row & 7)) * 8] = vv[p];
        }
        // e tile
        #pragma unroll
        for (int half = 0; half < 2; ++half) {
            bf16x8 e8;
            #pragma unroll
            for (int i = 0; i < 8; ++i) {
                float sc = sqv + skc[half * 8 + i];
                sc = sc > 0.f ? sc : 0.01f * sc;
                float e = __expf(sc * mk[half * 8 + i]);
                psum += e;
                e8[i] = (__bf16)e;
            }
            int lc = cq * 2 + half;
            *(bf16x8*)&eA[mrow * 64 + ((lc ^ (mrow & 7)) * 8)] = e8;
        }
        __syncthreads();
        int cn = (c0 + 64) & 1023;
        load_mask(cn);       // HBM stream first (longest latency)
        load_v(cn);          // L2/L3
        #pragma unroll
        for (int kb = 0; kb < 2; ++kb) {
            int lc = kb * 4 + quad;
            bf16x8 afr[4];
            #pragma unroll
            for (int rt = 0; rt < 4; ++rt)
                afr[rt] = *(const bf16x8*)&eA[(16 * rt + l15) * 64 + ((lc ^ (l15 & 7)) * 8)];
            #pragma unroll
            for (int ct = 0; ct < 4; ++ct) {
                int row = 64 * wv + 16 * ct + l15;
                bf16x8 bfr = *(const bf16x8*)&vB[row * 64 + ((lc ^ (row & 7)) * 8)];
                #pragma unroll
                for (int rt = 0; rt < 4; ++rt)
                    acc[rt][ct] = MFMA16(afr[rt], bfr, acc[rt][ct]);
            }
        }
        __syncthreads();
    }

    // partial rowsum (4 threads per row hold disjoint column partials)
    float rs = psum;
    rs += __shfl_xor(rs, 1);
    rs += __shfl_xor(rs, 2);
    float* rowsum = (float*)eA;
    if ((t & 3) == 0) rowsum[mrow] = rs;

    // pack acc -> obuf (vB region) [64][256] bf16 with chunk-xor swizzle
    __bf16* obuf = vB;
    #pragma unroll
    for (int rt = 0; rt < 4; ++rt) {
        #pragma unroll
        for (int j = 0; j < 4; ++j) {
            int m = 16 * rt + quad * 4 + j;
            #pragma unroll
            for (int ct = 0; ct < 4; ++ct) {
                int col = 64 * wv + 16 * ct + l15;
                int c8 = col >> 3;
                int pc = (c8 & 24) | ((c8 & 7) ^ (m & 7));
                obuf[m * 256 + pc * 8 + (col & 7)] = (__bf16)acc[rt][ct][j];
            }
        }
    }
    __syncthreads();

    if (t < 64)
        rsP[((size_t)(which * 2 + ch)) * 16384 + b * 2048 + m0 + t] = rowsum[t];

    __bf16* Pbase = ch ? P1 : P0;
    int m = t >> 2, sl = t & 3;
    __bf16* prow = Pbase + (size_t)(b * 2048 + m0 + m) * 512 + which * 256 + sl * 64;
    #pragma unroll
    for (int k = 0; k < 8; ++k) {
        int c8 = sl * 8 + k;
        int pc = (c8 & 24) | ((c8 & 7) ^ (m & 7));
        *(bf16x8*)(prow + k * 8) = *(const bf16x8*)&obuf[m * 256 + pc * 8];
    }
}

// ---------------------------------------------------------------------------
// K5: combine partials + output GEMM.
//   wf[n][k] = (P0[n][k] + P1[n][k]) * inv(rs0+rs1)   (bf16, k in [0,512))
//   out[n][d] = wf[n][:] . Wcat[d][:] + b_total[d]
// Note P1 lives in d_out: all P1 reads for a block's rows happen before the
// epilogue writes those same rows, and no other block touches them.
// ---------------------------------------------------------------------------
__global__ __launch_bounds__(256, 2) void k5_out(
    const __bf16* __restrict__ P0, const __bf16* __restrict__ P1,
    const float* __restrict__ rsP, const __bf16* __restrict__ Wcat,
    const float* __restrict__ b_total, float* __restrict__ out)
{
    __shared__ __attribute__((aligned(16))) __bf16 As[64][72];
    __shared__ __attribute__((aligned(16))) __bf16 Bs[256][72];
    __shared__ float bias[256];
    __shared__ float invs[2][64];
    int t = threadIdx.x;
    int n0 = blockIdx.x * 64;
    int lane = t & 63, wv = t >> 6, l15 = lane & 15, qo = (lane >> 4) * 8;
    bias[t] = b_total[t];
    if (t < 128) {
        int br = t >> 6, row = t & 63;
        float rs = rsP[(size_t)(br * 2) * 16384 + n0 + row] +
                   rsP[(size_t)(br * 2 + 1) * 16384 + n0 + row];
        invs[br][row] = __builtin_amdgcn_rcpf(rs);
    }
    __syncthreads();

    int arow = t >> 2, axs = (t & 3) * 16;
    int brr = t >> 3, bac = (t & 7) * 8;
    f32x4 acc[4][4] = {};

    for (int k0 = 0; k0 < 512; k0 += 64) {
        int br = k0 >> 8;
        float inv = invs[br][arow];
        #pragma unroll
        for (int u = 0; u < 2; ++u) {
            bf16x8 a0 = *(const bf16x8*)(P0 + (size_t)(n0 + arow) * 512 + k0 + axs + u * 8);
            bf16x8 a1 = *(const bf16x8*)(P1 + (size_t)(n0 + arow) * 512 + k0 + axs + u * 8);
            bf16x8 o;
            #pragma unroll
            for (int i = 0; i < 8; ++i)
                o[i] = (__bf16)(((float)a0[i] + (float)a1[i]) * inv);
            *(bf16x8*)&As[arow][axs + u * 8] = o;
        }
        #pragma unroll
        for (int p = 0; p < 8; ++p)
            *(bf16x8*)&Bs[p * 32 + brr][bac] =
                *(const bf16x8*)(Wcat + (size_t)(p * 32 + brr) * 512 + k0 + bac);
        __syncthreads();
        #pragma unroll
        for (int kb = 0; kb < 2; ++kb) {
            bf16x8 afr[4];
            #pragma unroll
            for (int rt = 0; rt < 4; ++rt)
                afr[rt] = *(const bf16x8*)&As[16 * rt + l15][kb * 32 + qo];
            #pragma unroll
            for (int ct = 0; ct < 4; ++ct) {
                bf16x8 bfr = *(const bf16x8*)&Bs[64 * wv + 16 * ct + l15][kb * 32 + qo];
                #pragma unroll
                for (int rt = 0; rt < 4; ++rt)
                    acc[rt][ct] = MFMA16(afr[rt], bfr, acc[rt][ct]);
            }
        }
        __syncthreads();
    }
    #pragma unroll
    for (int rt = 0; rt < 4; ++rt) {
        #pragma unroll
        for (int ct = 0; ct < 4; ++ct) {
            int d = 64 * wv + 16 * ct + l15;
            float bv = bias[d];
            #pragma unroll
            for (int j = 0; j < 4; ++j) {
                int m = 16 * rt + (lane >> 4) * 4 + j;
                out[(size_t)(n0 + m) * 256 + d] = acc[rt][ct][j] + bv;
            }
        }
    }
}

// ---------------------------------------------------------------------------
extern "C" void kernel_launch(void* const* d_in, const int* in_sizes, int n_in,
                              void* d_out, int out_size, void* d_ws, size_t ws_size,
                              hipStream_t stream)
{
    const float* op_feat  = (const float*)d_in[0];
    const float* mach_feat= (const float*)d_in[1];
    const float* tmask    = (const float*)d_in[2];
    const float* smask    = (const float*)d_in[3];
    const float* oma_q_w  = (const float*)d_in[4];
    const float* oma_q_b  = (const float*)d_in[5];
    const float* oma_kv_w = (const float*)d_in[6];
    const float* oma_kv_b = (const float*)d_in[7];
    const float* oma_s_w  = (const float*)d_in[8];
    const float* oma_s_b  = (const float*)d_in[9];
    const float* oma_o_w  = (const float*)d_in[10];
    const float* oma_o_b  = (const float*)d_in[11];
    const float* sa_w_w   = (const float*)d_in[12];
    const float* sa_w_b   = (const float*)d_in[13];
    const float* sa_s_w   = (const float*)d_in[14];
    const float* sa_s_b   = (const float*)d_in[15];
    const float* sa_o_w   = (const float*)d_in[16];
    const float* sa_o_b   = (const float*)d_in[17];
    const float* mix_w    = (const float*)d_in[18];
    const float* mix_b    = (const float*)d_in[19];

    char* ws = (char*)d_ws;
    float* wq_v   = (float*)(ws + 0);
    float* wk_v   = (float*)(ws + 1024);
    float* wq2_v  = (float*)(ws + 2048);
    float* wk2_v  = (float*)(ws + 3072);
    float* sb     = (float*)(ws + 4096);
    float* btot   = (float*)(ws + 4352);
    float* sqp    = (float*)(ws + 8192);
    float* skv    = (float*)(ws + 73728);
    float* sq2p   = (float*)(ws + 139264);
    float* sk2v   = (float*)(ws + 204800);
    __bf16* Wcat  = (__bf16*)(ws + 270336);    // 256 KB
    float* rsP    = (float*)(ws + 532480);     // 256 KB : [4][16384] f32
    __bf16* vt    = (__bf16*)(ws + 794624);    //  16 MB : [2][8][256][2048]
    __bf16* P0    = (__bf16*)(ws + 17571840);  //  16 MB : [16384][512] bf16
    __bf16* P1    = (__bf16*)d_out;            //  16 MB : d_out as scratch
    float* outp   = (float*)d_out;

    k0_vectors<<<4, 256, 0, stream>>>(oma_q_w, oma_q_b, oma_kv_w, oma_kv_b,
                                      oma_s_w, oma_s_b, sa_w_w, sa_w_b,
                                      sa_s_w, sa_s_b, wq_v, wk_v, wq2_v, wk2_v, sb);
    k1_wcat<<<256, 256, 0, stream>>>(mix_w, mix_b, oma_o_w, oma_o_b,
                                     sa_o_w, sa_o_b, Wcat, btot);
    k2_scores<<<4096, 256, 0, stream>>>(op_feat, mach_feat, wq_v, wk_v, wq2_v, wk2_v,
                                        sb, sqp, skv, sq2p, sk2v);
    k3_vgemm<<<512, 256, 0, stream>>>(op_feat, mach_feat, oma_kv_w, sa_w_w, vt);
    k4_attn<<<1024, 256, 0, stream>>>(tmask, smask, sqp, skv, sq2p, sk2v, vt,
                                      P0, P1, rsP);
    k5_out<<<256, 256, 0, stream>>>(P0, P1, rsP, Wcat, btot, outp);
}

// Round 4
// 466.548 us; speedup vs baseline: 1.2019x; 1.1226x over previous
//
#include <hip/hip_runtime.h>
#include <stdint.h>
#include <stddef.h>

#define B_ 8
#define N_ 2048
#define C_ 2048
#define D_ 256
#define H_ 256

typedef __bf16 bf16x8 __attribute__((ext_vector_type(8)));
typedef __bf16 bf16x4 __attribute__((ext_vector_type(4)));
typedef float f32x4 __attribute__((ext_vector_type(4)));

#define MFMA16(a, b, c) __builtin_amdgcn_mfma_f32_16x16x32_bf16((a), (b), (c), 0, 0, 0)

// ---------------------------------------------------------------------------
// K_pack: bit-pack masks (values are exactly 0.0/1.0 -> 1 bit each).
// Layout: bm[which][b][row][64 dwords], bit c%32 of dword c/32.
// 268 MB fp32 in -> 8.4 MB bits out; pure stream.
// ---------------------------------------------------------------------------
__global__ __launch_bounds__(256) void k_pack(
    const float* __restrict__ tmask, const float* __restrict__ smask,
    uint32_t* __restrict__ bm)
{
    size_t w = (size_t)blockIdx.x * 256 + threadIdx.x;   // 2*8*2048*64 words
    int which = w >= 1048576u;
    const float* src = (which ? smask : tmask) + (size_t)(w & 1048575u) * 32;
    uint32_t bits = 0;
    #pragma unroll
    for (int i = 0; i < 8; ++i) {
        float4 v = *(const float4*)(src + i * 4);
        bits |= (v.x != 0.f ? 1u : 0u) << (i * 4);
        bits |= (v.y != 0.f ? 1u : 0u) << (i * 4 + 1);
        bits |= (v.z != 0.f ? 1u : 0u) << (i * 4 + 2);
        bits |= (v.w != 0.f ? 1u : 0u) << (i * 4 + 3);
    }
    bm[w] = bits;
}

// ---------------------------------------------------------------------------
// K0: collapse score projections to vectors (rank-1 score factorization).
// ---------------------------------------------------------------------------
__global__ __launch_bounds__(256) void k0_vectors(
    const float* __restrict__ oma_q_w, const float* __restrict__ oma_q_b,
    const float* __restrict__ oma_kv_w, const float* __restrict__ oma_kv_b,
    const float* __restrict__ oma_s_w, const float* __restrict__ oma_s_b,
    const float* __restrict__ sa_w_w, const float* __restrict__ sa_w_b,
    const float* __restrict__ sa_s_w, const float* __restrict__ sa_s_b,
    float* __restrict__ wq_v, float* __restrict__ wk_v,
    float* __restrict__ wq2_v, float* __restrict__ wk2_v,
    float* __restrict__ sb)
{
    int d = threadIdx.x;
    int w = blockIdx.x;
    const float* M;
    const float* svec;
    float* outv;
    if (w == 0)      { M = oma_q_w;            svec = oma_s_w;       outv = wq_v;  }
    else if (w == 1) { M = oma_kv_w;           svec = oma_s_w + 256; outv = wk_v;  }
    else if (w == 2) { M = sa_w_w;             svec = sa_s_w;        outv = wq2_v; }
    else             { M = sa_w_w + 256 * 256; svec = sa_s_w + 256;  outv = wk2_v; }
    float a = 0.f;
    #pragma unroll 8
    for (int h = 0; h < 256; ++h)
        a += M[h * 256 + d] * svec[h];
    outv[d] = a;

    if (w == 0) {
        int h = d;
        float p1 = oma_q_b[h] * oma_s_w[h] + oma_kv_b[h] * oma_s_w[256 + h];
        float p2 = sa_w_b[h] * sa_s_w[h] + sa_w_b[256 + h] * sa_s_w[256 + h];
        for (int o = 32; o; o >>= 1) { p1 += __shfl_xor(p1, o); p2 += __shfl_xor(p2, o); }
        __shared__ float redA[4], redB[4];
        int wvv = threadIdx.x >> 6;
        if ((threadIdx.x & 63) == 0) { redA[wvv] = p1; redB[wvv] = p2; }
        __syncthreads();
        if (threadIdx.x == 0) {
            sb[0] = redA[0] + redA[1] + redA[2] + redA[3] + oma_s_b[0];
            sb[1] = redB[0] + redB[1] + redB[2] + redB[3] + sa_s_b[0];
        }
    }
}

// ---------------------------------------------------------------------------
// K1: fold output projections through mix -> Wcat (bf16) + b_total.
// ---------------------------------------------------------------------------
__global__ __launch_bounds__(256) void k1_wcat(
    const float* __restrict__ mix_w, const float* __restrict__ mix_b,
    const float* __restrict__ oma_o_w, const float* __restrict__ oma_o_b,
    const float* __restrict__ sa_o_w, const float* __restrict__ sa_o_b,
    __bf16* __restrict__ Wcat, float* __restrict__ b_total)
{
    int d = blockIdx.x, h = threadIdx.x;
    const float* mwr = mix_w + d * 512;
    float w1 = 0.f, w2 = 0.f;
    for (int e = 0; e < 256; ++e) {
        w1 += mwr[e] * oma_o_w[e * 256 + h];
        w2 += mwr[256 + e] * sa_o_w[e * 256 + h];
    }
    Wcat[d * 512 + h] = (__bf16)w1;
    Wcat[d * 512 + 256 + h] = (__bf16)w2;

    float pb = mwr[h] * oma_o_b[h] + mwr[256 + h] * sa_o_b[h];
    for (int o = 32; o; o >>= 1) pb += __shfl_xor(pb, o);
    __shared__ float red[4];
    if ((h & 63) == 0) red[h >> 6] = pb;
    __syncthreads();
    if (h == 0) b_total[d] = mix_b[d] + red[0] + red[1] + red[2] + red[3];
}

// ---------------------------------------------------------------------------
// K2: per-row score scalars (one wave per row).
// ---------------------------------------------------------------------------
__global__ __launch_bounds__(256) void k2_scores(
    const float* __restrict__ op, const float* __restrict__ mach,
    const float* __restrict__ wq_v, const float* __restrict__ wk_v,
    const float* __restrict__ wq2_v, const float* __restrict__ wk2_v,
    const float* __restrict__ sb,
    float* __restrict__ sqp, float* __restrict__ skv,
    float* __restrict__ sq2p, float* __restrict__ sk2v)
{
    int t = threadIdx.x, lane = t & 63, wv = t >> 6;
    size_t n = (size_t)blockIdx.x * 4 + wv;
    const float4 mf = *(const float4*)(mach + n * 256 + lane * 4);
    const float4 of = *(const float4*)(op + n * 256 + lane * 4);
    const float4 q4 = *(const float4*)(wq_v + lane * 4);
    const float4 k4 = *(const float4*)(wk_v + lane * 4);
    const float4 q24 = *(const float4*)(wq2_v + lane * 4);
    const float4 k24 = *(const float4*)(wk2_v + lane * 4);
    float s1 = mf.x * q4.x + mf.y * q4.y + mf.z * q4.z + mf.w * q4.w;
    float s2 = of.x * k4.x + of.y * k4.y + of.z * k4.z + of.w * k4.w;
    float s3 = mf.x * q24.x + mf.y * q24.y + mf.z * q24.z + mf.w * q24.w;
    float s4 = mf.x * k24.x + mf.y * k24.y + mf.z * k24.z + mf.w * k24.w;
    for (int o = 32; o; o >>= 1) {
        s1 += __shfl_xor(s1, o); s2 += __shfl_xor(s2, o);
        s3 += __shfl_xor(s3, o); s4 += __shfl_xor(s4, o);
    }
    if (lane == 0) {
        sqp[n] = s1 + sb[0]; skv[n] = s2;
        sq2p[n] = s3 + sb[1]; sk2v[n] = s4;
    }
}

// ---------------------------------------------------------------------------
// K3: value projections -> vt[which][b][h][c] (bf16). One block per
// (which,b,c-tile 64); stages X tile once, loops the 4 weight h-tiles.
// ---------------------------------------------------------------------------
__global__ __launch_bounds__(256, 2) void k3_vgemm(
    const float* __restrict__ op, const float* __restrict__ mach,
    const float* __restrict__ oma_kv_w, const float* __restrict__ sa_w_w,
    __bf16* __restrict__ vt)
{
    __shared__ __attribute__((aligned(16))) __bf16 Xs[64][264];
    __shared__ __attribute__((aligned(16))) __bf16 As[64][264];
    int t = threadIdx.x;
    int bid = blockIdx.x;
    int which = bid >> 8;
    int r = bid & 255;
    int b = r >> 5;
    int ct = r & 31;

    const float* Wbase = which ? (sa_w_w + 512 * 256) : (oma_kv_w + 256 * 256);
    const float* Xglob = (which ? mach : op) + ((size_t)b * N_ + ct * 64) * 256;

    int lane = t & 63, wv = t >> 6;
    int l15 = lane & 15, qo = (lane >> 4) * 8;

    #pragma unroll
    for (int p = 0; p < 16; ++p) {
        int row = p * 4 + wv;
        float4 xv = *(const float4*)(Xglob + (size_t)row * 256 + lane * 4);
        bf16x4 x4;
        x4[0] = (__bf16)xv.x; x4[1] = (__bf16)xv.y; x4[2] = (__bf16)xv.z; x4[3] = (__bf16)xv.w;
        *(bf16x4*)&Xs[row][lane * 4] = x4;
    }

    for (int ht = 0; ht < 4; ++ht) {
        __syncthreads();
        const float* Ag = Wbase + (size_t)ht * 64 * 256;
        #pragma unroll
        for (int p = 0; p < 16; ++p) {
            int row = p * 4 + wv;
            float4 av = *(const float4*)(Ag + (size_t)row * 256 + lane * 4);
            bf16x4 a4;
            a4[0] = (__bf16)av.x; a4[1] = (__bf16)av.y; a4[2] = (__bf16)av.z; a4[3] = (__bf16)av.w;
            *(bf16x4*)&As[row][lane * 4] = a4;
        }
        __syncthreads();

        f32x4 acc[4] = {};
        #pragma unroll
        for (int kb = 0; kb < 8; ++kb) {
            bf16x8 bfr = *(const bf16x8*)&Xs[16 * wv + l15][kb * 32 + qo];
            #pragma unroll
            for (int rt = 0; rt < 4; ++rt) {
                bf16x8 afr = *(const bf16x8*)&As[16 * rt + l15][kb * 32 + qo];
                acc[rt] = MFMA16(afr, bfr, acc[rt]);
            }
        }
        __syncthreads();

        #pragma unroll
        for (int rt = 0; rt < 4; ++rt)
            #pragma unroll
            for (int j = 0; j < 4; ++j)
                As[16 * rt + (lane >> 4) * 4 + j][16 * wv + l15] = (__bf16)acc[rt][j];
        __syncthreads();

        int hh = t >> 2, cb = (t & 3) * 16;
        __bf16* orow = vt + (((size_t)(which * 8 + b)) * 256 + ht * 64 + hh) * 2048 + ct * 64 + cb;
        *(bf16x8*)(orow) = *(const bf16x8*)&As[hh][cb];
        *(bf16x8*)(orow + 8) = *(const bf16x8*)&As[hh][cb + 8];
    }
}

// ---------------------------------------------------------------------------
// K4: fused masked-softmax attention, R0 structure (m-tile 64, full c-range,
// grid 512) but mask comes from the 8.4 MB bitmask (4B/thread/chunk from
// L1/L2) instead of a 268 MB fp32 HBM stream. XOR-swizzled pad-free LDS
// (40960 B). e = bit ? exp(leaky(sq+sk)) : 1  == exp(leaky(sq+sk)*mask).
// ---------------------------------------------------------------------------
__global__ __launch_bounds__(256, 2) void k4_attn(
    const uint32_t* __restrict__ bm,
    const float* __restrict__ sqp, const float* __restrict__ skv,
    const float* __restrict__ sq2p, const float* __restrict__ sk2v,
    const __bf16* __restrict__ vt,
    __bf16* __restrict__ wfcat)
{
    __shared__ __attribute__((aligned(16))) __bf16 eA[64 * 64];   //  8 KB
    __shared__ __attribute__((aligned(16))) __bf16 vB[256 * 64];  // 32 KB

    int t = threadIdx.x;
    int bid = blockIdx.x;
    int which = bid >> 8;
    int r = bid & 255;
    int b = r >> 5;
    int m0 = (r & 31) * 64;

    const float* sqrow = (which ? sq2p : sqp) + b * N_ + m0;
    const float* skrow = (which ? sk2v : skv) + b * N_;
    const __bf16* vbase = vt + ((size_t)(which * 8 + b)) * 256 * 2048;

    int lane = t & 63, wv = t >> 6;
    int l15 = lane & 15, quad = lane >> 4;
    int mrow = t >> 2, cq = t & 3;       // e tile: row 0..63, 16-col slice
    int vh = t >> 3, vcc = t & 7;        // v staging: row group, 16B chunk

    const uint32_t* bmrow = bm + ((size_t)(which * 8 + b) * 2048 + m0 + mrow) * 64;

    float sqv = sqrow[mrow];
    float psum = 0.f;
    f32x4 acc[4][4] = {};
    bf16x8 vv[8];
    float skc[16];
    uint32_t wb;

    auto load_sc = [&](int c0) {
        #pragma unroll
        for (int i = 0; i < 4; ++i) {
            float4 s4 = *(const float4*)(skrow + c0 + cq * 16 + i * 4);
            skc[4 * i + 0] = s4.x; skc[4 * i + 1] = s4.y;
            skc[4 * i + 2] = s4.z; skc[4 * i + 3] = s4.w;
        }
        wb = bmrow[(c0 >> 5) + (cq >> 1)] >> ((cq & 1) * 16);
    };
    auto load_v = [&](int c0) {
        #pragma unroll
        for (int p = 0; p < 8; ++p)
            vv[p] = *(const bf16x8*)(vbase + (size_t)(p * 32 + vh) * 2048 + c0 + vcc * 8);
    };
    load_sc(0);
    load_v(0);

    for (int c0 = 0; c0 < C_; c0 += 64) {
        // stage v tile (phys chunk = vcc ^ (row&7))
        #pragma unroll
        for (int p = 0; p < 8; ++p) {
            int row = p * 32 + vh;
            *(bf16x8*)&vB[row * 64 + ((vcc ^ (row & 7)) * 8)] = vv[p];
        }
        // e tile
        #pragma unroll
        for (int half = 0; half < 2; ++half) {
            bf16x8 e8;
            #pragma unroll
            for (int i = 0; i < 8; ++i) {
                int ii = half * 8 + i;
                float s = sqv + skc[ii];
                s = s > 0.f ? s : 0.01f * s;
                float es = __expf(s);
                float e = ((wb >> ii) & 1u) ? es : 1.0f;
                psum += e;
                e8[i] = (__bf16)e;
            }
            int lc = cq * 2 + half;
            *(bf16x8*)&eA[mrow * 64 + ((lc ^ (mrow & 7)) * 8)] = e8;
        }
        __syncthreads();
        int cn = (c0 + 64) & 2047;
        load_sc(cn);
        load_v(cn);
        #pragma unroll
        for (int kb = 0; kb < 2; ++kb) {
            int lc = kb * 4 + quad;
            bf16x8 afr[4];
            #pragma unroll
            for (int rt = 0; rt < 4; ++rt)
                afr[rt] = *(const bf16x8*)&eA[(16 * rt + l15) * 64 + ((lc ^ (l15 & 7)) * 8)];
            #pragma unroll
            for (int ct = 0; ct < 4; ++ct) {
                int row = 64 * wv + 16 * ct + l15;
                bf16x8 bfr = *(const bf16x8*)&vB[row * 64 + ((lc ^ (row & 7)) * 8)];
                #pragma unroll
                for (int rt = 0; rt < 4; ++rt)
                    acc[rt][ct] = MFMA16(afr[rt], bfr, acc[rt][ct]);
            }
        }
        __syncthreads();
    }

    // rowsum: 4 threads per row hold disjoint column partials
    float rs = psum;
    rs += __shfl_xor(rs, 1);
    rs += __shfl_xor(rs, 2);
    float* rowsum = (float*)eA;
    if ((t & 3) == 0) rowsum[mrow] = rs;
    __syncthreads();

    // normalize, pack [64][256] into vB (chunk-xor swizzle), coalesced store
    __bf16* obuf = vB;
    #pragma unroll
    for (int rt = 0; rt < 4; ++rt) {
        #pragma unroll
        for (int j = 0; j < 4; ++j) {
            int m = 16 * rt + quad * 4 + j;
            float inv = __builtin_amdgcn_rcpf(rowsum[m]);
            #pragma unroll
            for (int ct = 0; ct < 4; ++ct) {
                int col = 64 * wv + 16 * ct + l15;
                int c8 = col >> 3;
                int pc = (c8 & 24) | ((c8 & 7) ^ (m & 7));
                obuf[m * 256 + pc * 8 + (col & 7)] = (__bf16)(acc[rt][ct][j] * inv);
            }
        }
    }
    __syncthreads();
    int m = t >> 2, sl = t & 3;
    __bf16* wrow = wfcat + (size_t)(b * N_ + m0 + m) * 512 + which * 256 + sl * 64;
    #pragma unroll
    for (int k = 0; k < 8; ++k) {
        int c8 = sl * 8 + k;
        int pc = (c8 & 24) | ((c8 & 7) ^ (m & 7));
        *(bf16x8*)(wrow + k * 8) = *(const bf16x8*)&obuf[m * 256 + pc * 8];
    }
}

// ---------------------------------------------------------------------------
// K5: out[n][d] = wfcat[n][:512] . Wcat[d][:512] + b_total[d]   (fp32 out)
// ---------------------------------------------------------------------------
__global__ __launch_bounds__(256, 2) void k5_out(
    const __bf16* __restrict__ wfcat, const __bf16* __restrict__ Wcat,
    const float* __restrict__ b_total, float* __restrict__ out)
{
    __shared__ __attribute__((aligned(16))) __bf16 As[64][72];
    __shared__ __attribute__((aligned(16))) __bf16 Bs[256][72];
    __shared__ float bias[256];
    int t = threadIdx.x;
    int n0 = blockIdx.x * 64;
    int lane = t & 63, wv = t >> 6, l15 = lane & 15, qo = (lane >> 4) * 8;
    bias[t] = b_total[t];
    int ar = t >> 3;          // 0..31
    int ac = (t & 7) * 8;
    f32x4 acc[4][4] = {};

    for (int k0 = 0; k0 < 512; k0 += 64) {
        #pragma unroll
        for (int p = 0; p < 2; ++p)
            *(bf16x8*)&As[p * 32 + ar][ac] =
                *(const bf16x8*)(wfcat + (size_t)(n0 + p * 32 + ar) * 512 + k0 + ac);
        #pragma unroll
        for (int p = 0; p < 8; ++p)
            *(bf16x8*)&Bs[p * 32 + ar][ac] =
                *(const bf16x8*)(Wcat + (size_t)(p * 32 + ar) * 512 + k0 + ac);
        __syncthreads();
        #pragma unroll
        for (int kb = 0; kb < 2; ++kb) {
            bf16x8 afr[4];
            #pragma unroll
            for (int rt = 0; rt < 4; ++rt)
                afr[rt] = *(const bf16x8*)&As[16 * rt + l15][kb * 32 + qo];
            #pragma unroll
            for (int ct = 0; ct < 4; ++ct) {
                bf16x8 bfr = *(const bf16x8*)&Bs[64 * wv + 16 * ct + l15][kb * 32 + qo];
                #pragma unroll
                for (int rt = 0; rt < 4; ++rt)
                    acc[rt][ct] = MFMA16(afr[rt], bfr, acc[rt][ct]);
            }
        }
        __syncthreads();
    }
    #pragma unroll
    for (int rt = 0; rt < 4; ++rt) {
        #pragma unroll
        for (int ct = 0; ct < 4; ++ct) {
            int d = 64 * wv + 16 * ct + l15;
            float bv = bias[d];
            #pragma unroll
            for (int j = 0; j < 4; ++j) {
                int m = 16 * rt + (lane >> 4) * 4 + j;
                out[(size_t)(n0 + m) * 256 + d] = acc[rt][ct][j] + bv;
            }
        }
    }
}

// ---------------------------------------------------------------------------
extern "C" void kernel_launch(void* const* d_in, const int* in_sizes, int n_in,
                              void* d_out, int out_size, void* d_ws, size_t ws_size,
                              hipStream_t stream)
{
    const float* op_feat  = (const float*)d_in[0];
    const float* mach_feat= (const float*)d_in[1];
    const float* tmask    = (const float*)d_in[2];
    const float* smask    = (const float*)d_in[3];
    const float* oma_q_w  = (const float*)d_in[4];
    const float* oma_q_b  = (const float*)d_in[5];
    const float* oma_kv_w = (const float*)d_in[6];
    const float* oma_kv_b = (const float*)d_in[7];
    const float* oma_s_w  = (const float*)d_in[8];
    const float* oma_s_b  = (const float*)d_in[9];
    const float* oma_o_w  = (const float*)d_in[10];
    const float* oma_o_b  = (const float*)d_in[11];
    const float* sa_w_w   = (const float*)d_in[12];
    const float* sa_w_b   = (const float*)d_in[13];
    const float* sa_s_w   = (const float*)d_in[14];
    const float* sa_s_b   = (const float*)d_in[15];
    const float* sa_o_w   = (const float*)d_in[16];
    const float* sa_o_b   = (const float*)d_in[17];
    const float* mix_w    = (const float*)d_in[18];
    const float* mix_b    = (const float*)d_in[19];

    char* ws = (char*)d_ws;
    float* wq_v   = (float*)(ws + 0);
    float* wk_v   = (float*)(ws + 1024);
    float* wq2_v  = (float*)(ws + 2048);
    float* wk2_v  = (float*)(ws + 3072);
    float* sb     = (float*)(ws + 4096);
    float* btot   = (float*)(ws + 4352);
    float* sqp    = (float*)(ws + 8192);
    float* skv    = (float*)(ws + 73728);
    float* sq2p   = (float*)(ws + 139264);
    float* sk2v   = (float*)(ws + 204800);
    __bf16* Wcat  = (__bf16*)(ws + 270336);    // 256 KB
    __bf16* vt    = (__bf16*)(ws + 532480);    //  16 MB : [2][8][256][2048]
    __bf16* wfcat = (__bf16*)(ws + 17309696);  //  16 MB : [16384][512]
    uint32_t* bmp = (uint32_t*)d_out;          // 8.4 MB bitmask in d_out
    float* outp   = (float*)d_out;             // k5 overwrites at the end

    k_pack<<<8192, 256, 0, stream>>>(tmask, smask, bmp);
    k0_vectors<<<4, 256, 0, stream>>>(oma_q_w, oma_q_b, oma_kv_w, oma_kv_b,
                                      oma_s_w, oma_s_b, sa_w_w, sa_w_b,
                                      sa_s_w, sa_s_b, wq_v, wk_v, wq2_v, wk2_v, sb);
    k1_wcat<<<256, 256, 0, stream>>>(mix_w, mix_b, oma_o_w, oma_o_b,
                                     sa_o_w, sa_o_b, Wcat, btot);
    k2_scores<<<4096, 256, 0, stream>>>(op_feat, mach_feat, wq_v, wk_v, wq2_v, wk2_v,
                                        sb, sqp, skv, sq2p, sk2v);
    k3_vgemm<<<512, 256, 0, stream>>>(op_feat, mach_feat, oma_kv_w, sa_w_w, vt);
    k4_attn<<<512, 256, 0, stream>>>(bmp, sqp, skv, sq2p, sk2v, vt, wfcat);
    k5_out<<<256, 256, 0, stream>>>(wfcat, Wcat, btot, outp);
}